// Round 2
// baseline (563.089 us; speedup 1.0000x reference)
//
#include <hip/hip_runtime.h>
#include <hip/hip_bf16.h>

// Shapes
#define B_    64
#define C_    768
#define T_    1024
#define K_    800
#define KPAD  896     // pad 800 -> 7 * 128
#define MT    64      // token rows per block (A panel resident in LDS)
#define NT    128     // proto cols per n-tile
#define NTILES 7      // KPAD / NT
#define BK    64      // k-step (c) per stage
#define KSTEPS 12     // C_ / BK
#define TCH   16      // T_ / MT

using bf16x8 = __attribute__((ext_vector_type(8))) short;
using f32x4  = __attribute__((ext_vector_type(4))) float;

// ---------------- kernel P: normalize prototypes -> bf16, pad rows 800..895 with 0
__global__ __launch_bounds__(64) void proto_norm_kernel(const float* __restrict__ protos,
                                                        unsigned short* __restrict__ pn) {
    const int row = blockIdx.x;
    const int l = threadIdx.x;
    if (row >= K_) {
        for (int i = 0; i < 12; ++i) pn[(size_t)row * C_ + l + 64 * i] = 0;
        return;
    }
    float v[12];
    float ss = 0.f;
    for (int i = 0; i < 12; ++i) {
        v[i] = protos[(size_t)row * C_ + l + 64 * i];
        ss += v[i] * v[i];
    }
    for (int off = 32; off >= 1; off >>= 1) ss += __shfl_xor(ss, off);
    const float scale = 1.0f / fmaxf(sqrtf(ss), 1e-6f);
    for (int i = 0; i < 12; ++i) {
        __hip_bfloat16 h = __float2bfloat16(v[i] * scale);
        pn[(size_t)row * C_ + l + 64 * i] = *reinterpret_cast<unsigned short*>(&h);
    }
}

// ---------------- main kernel: per (b, 64-token chunk): A-resident GEMM + partial LSE over rows
__global__ __launch_bounds__(512, 2) void main_kernel(
        const float* __restrict__ feats, const unsigned short* __restrict__ pn,
        const float* __restrict__ log_temp,
        float* __restrict__ wsm, float* __restrict__ wss) {

    __shared__ char  Alds[MT * 1536];   // [t][c] bf16, row stride 1536B, byte ^= (t&7)<<4
    __shared__ char  Blds[NT * 128];    // [n][64 c] bf16, row 128B, chunk s stored at s^(n&7)
    __shared__ float ss_lds[MT];
    __shared__ float scale_lds[MT];
    __shared__ float red[8][2][16][2];

    const int tid = threadIdx.x;
    const int l   = tid & 63;
    const int w   = tid >> 6;     // wave 0..7
    const int g   = l >> 4;       // lane group 0..3
    const int lm  = l & 15;
    const int wm  = w >> 2;       // 0..1 (m half)
    const int wn  = w & 3;        // 0..3 (n quarter)

    const int bb = blockIdx.x >> 4;
    const int tc = blockIdx.x & 15;
    const int t0 = tc * MT;

    if (tid < MT) ss_lds[tid] = 0.f;
    __syncthreads();

    // ---- stage A panel [64 t][768 c] as bf16 (transpose from [c][t]), fp32 sum-of-squares
    {
        const int t4    = tid & 15;   // float4 index along t (fixed per thread)
        const int cbase = tid >> 4;   // 0..31
        float ssp0 = 0.f, ssp1 = 0.f, ssp2 = 0.f, ssp3 = 0.f;
        const float* fb = feats + (size_t)bb * C_ * T_ + t0 + t4 * 4;
        for (int i = 0; i < 24; ++i) {
            const int c = cbase + 32 * i;
            float4 v = *reinterpret_cast<const float4*>(fb + (size_t)c * T_);
            const float vv[4] = {v.x, v.y, v.z, v.w};
            ssp0 += vv[0] * vv[0]; ssp1 += vv[1] * vv[1];
            ssp2 += vv[2] * vv[2]; ssp3 += vv[3] * vv[3];
            #pragma unroll
            for (int q = 0; q < 4; ++q) {
                const int t = t4 * 4 + q;
                unsigned byte = (unsigned)(t * 1536 + c * 2);
                byte ^= (unsigned)((t & 7) << 4);
                __hip_bfloat16 h = __float2bfloat16(vv[q]);
                *reinterpret_cast<unsigned short*>(&Alds[byte]) =
                    *reinterpret_cast<unsigned short*>(&h);
            }
        }
        atomicAdd(&ss_lds[t4 * 4 + 0], ssp0);
        atomicAdd(&ss_lds[t4 * 4 + 1], ssp1);
        atomicAdd(&ss_lds[t4 * 4 + 2], ssp2);
        atomicAdd(&ss_lds[t4 * 4 + 3], ssp3);
    }
    __syncthreads();
    if (tid < MT) {
        const float temp = fminf(fmaxf(expf(log_temp[0]), 1e-4f), 100.0f);
        scale_lds[tid] = temp / fmaxf(sqrtf(ss_lds[tid]), 1e-6f);
    }
    __syncthreads();

    for (int nt = 0; nt < NTILES; ++nt) {
        const int n0 = nt * NT;
        f32x4 acc[2][2] = {};

        for (int ks = 0; ks < KSTEPS; ++ks) {
            __syncthreads();   // protect Blds (and red on first step of a tile)
            // stage B tile [128 n][64 c] bf16, chunk-swizzled
            #pragma unroll
            for (int h = 0; h < 2; ++h) {
                const int chunk = tid + h * 512;      // 0..1023
                const int n = chunk >> 3, s = chunk & 7;
                const bf16x8 src = *reinterpret_cast<const bf16x8*>(
                    pn + (size_t)(n0 + n) * C_ + ks * BK + s * 8);
                const int dst = n * 128 + ((s ^ (n & 7)) << 4);
                *reinterpret_cast<bf16x8*>(&Blds[dst]) = src;
            }
            __syncthreads();

            #pragma unroll
            for (int kk = 0; kk < 2; ++kk) {
                bf16x8 a[2], b[2];
                #pragma unroll
                for (int mi = 0; mi < 2; ++mi) {
                    const int t = wm * 32 + mi * 16 + lm;
                    unsigned byte = (unsigned)(t * 1536 + (ks * 64 + kk * 32 + g * 8) * 2);
                    byte ^= (unsigned)((t & 7) << 4);
                    a[mi] = *reinterpret_cast<const bf16x8*>(&Alds[byte]);
                }
                #pragma unroll
                for (int ni = 0; ni < 2; ++ni) {
                    const int n = wn * 32 + ni * 16 + lm;
                    const int chunkc = (kk * 4 + g) ^ (n & 7);
                    b[ni] = *reinterpret_cast<const bf16x8*>(&Blds[n * 128 + chunkc * 16]);
                }
                #pragma unroll
                for (int mi = 0; mi < 2; ++mi)
                    #pragma unroll
                    for (int ni = 0; ni < 2; ++ni)
                        acc[mi][ni] = __builtin_amdgcn_mfma_f32_16x16x32_bf16(
                            a[mi], b[ni], acc[mi][ni], 0, 0, 0);
            }
        }

        // ---- epilogue: scale by temp/||token||, partial logsumexp over the 64 t-rows
        float4 sc[2];
        #pragma unroll
        for (int mi = 0; mi < 2; ++mi)
            sc[mi] = *reinterpret_cast<const float4*>(&scale_lds[wm * 32 + mi * 16 + g * 4]);

        #pragma unroll
        for (int ni = 0; ni < 2; ++ni) {
            float vals[8];
            float mloc = -3.0e38f;
            #pragma unroll
            for (int mi = 0; mi < 2; ++mi) {
                const float scv[4] = {sc[mi].x, sc[mi].y, sc[mi].z, sc[mi].w};
                #pragma unroll
                for (int r = 0; r < 4; ++r) {
                    const float v = acc[mi][ni][r] * scv[r];
                    vals[mi * 4 + r] = v;
                    mloc = fmaxf(mloc, v);
                }
            }
            float sloc = 0.f;
            #pragma unroll
            for (int i = 0; i < 8; ++i) sloc += expf(vals[i] - mloc);
            #pragma unroll
            for (int off = 16; off <= 32; off <<= 1) {
                const float mo = __shfl_xor(mloc, off);
                const float so = __shfl_xor(sloc, off);
                const float M = fmaxf(mloc, mo);
                sloc = sloc * expf(mloc - M) + so * expf(mo - M);
                mloc = M;
            }
            if (l < 16) { red[w][ni][lm][0] = mloc; red[w][ni][lm][1] = sloc; }
        }
        __syncthreads();
        if (wm == 0 && l < 16) {
            #pragma unroll
            for (int ni = 0; ni < 2; ++ni) {
                const float m0 = red[w][ni][lm][0],     s0 = red[w][ni][lm][1];
                const float m1 = red[w + 4][ni][lm][0], s1 = red[w + 4][ni][lm][1];
                const float M = fmaxf(m0, m1);
                const float S = s0 * expf(m0 - M) + s1 * expf(m1 - M);
                const int k = n0 + wn * 32 + ni * 16 + lm;
                const size_t idx = ((size_t)bb * TCH + tc) * KPAD + k;
                wsm[idx] = M;
                wss[idx] = S;
            }
        }
        // next iteration's first __syncthreads protects red reuse
    }
}

// ---------------- final: joint LSE over 16 chunks x 8 protos per class
__global__ __launch_bounds__(128) void final_kernel(const float* __restrict__ wsm,
                                                    const float* __restrict__ wss,
                                                    float* __restrict__ out) {
    const int b = blockIdx.x;
    const int c = threadIdx.x;
    if (c >= 100) return;
    float M = -3.0e38f, S = 0.f;
    for (int ch = 0; ch < TCH; ++ch) {
        const size_t base = ((size_t)b * TCH + ch) * KPAD + c * 8;
        #pragma unroll
        for (int p = 0; p < 8; ++p) {
            const float m = wsm[base + p], s = wss[base + p];
            const float Mn = fmaxf(M, m);
            S = S * expf(M - Mn) + s * expf(m - Mn);
            M = Mn;
        }
    }
    out[b * 100 + c] = M + logf(S);
}

extern "C" void kernel_launch(void* const* d_in, const int* in_sizes, int n_in,
                              void* d_out, int out_size, void* d_ws, size_t ws_size,
                              hipStream_t stream) {
    (void)in_sizes; (void)n_in; (void)out_size; (void)ws_size;
    const float* feats    = (const float*)d_in[0];
    const float* protos   = (const float*)d_in[1];
    const float* log_temp = (const float*)d_in[2];
    float* out = (float*)d_out;

    unsigned short* pn = (unsigned short*)d_ws;                       // 896*768 bf16
    float* wsm = (float*)((char*)d_ws + (size_t)KPAD * C_ * 2);       // 64*16*896 f32
    float* wss = wsm + (size_t)B_ * TCH * KPAD;

    proto_norm_kernel<<<KPAD, 64, 0, stream>>>(protos, pn);
    main_kernel<<<B_ * TCH, 512, 0, stream>>>(feats, pn, log_temp, wsm, wss);
    final_kernel<<<B_, 128, 0, stream>>>(wsm, wss, out);
}

// Round 3
// 436.093 us; speedup vs baseline: 1.2912x; 1.2912x over previous
//
#include <hip/hip_runtime.h>
#include <hip/hip_bf16.h>

// Shapes
#define B_    64
#define C_    768
#define T_    1024
#define K_    800
#define KPAD  896     // pad 800 -> 7 * 128
#define MT    64      // token rows per block (A panel resident in LDS)
#define NT    128     // proto cols per n-tile
#define NTILES 7      // KPAD / NT
#define KSTEPS 12     // C_ / 64
#define NSTEPS 84     // NTILES * KSTEPS
#define TCH   16      // T_ / MT

using bf16x8 = __attribute__((ext_vector_type(8))) short;
using f32x4  = __attribute__((ext_vector_type(4))) float;

__device__ __forceinline__ void gload16(const void* g, void* lds) {
    __builtin_amdgcn_global_load_lds(
        (const __attribute__((address_space(1))) unsigned int*)g,
        (__attribute__((address_space(3))) unsigned int*)lds, 16, 0, 0);
}

// ---------------- kernel P: normalize prototypes -> bf16, pad rows 800..895 with 0
__global__ __launch_bounds__(64) void proto_norm_kernel(const float* __restrict__ protos,
                                                        unsigned short* __restrict__ pn) {
    const int row = blockIdx.x;
    const int l = threadIdx.x;
    if (row >= K_) {
        for (int i = 0; i < 12; ++i) pn[(size_t)row * C_ + l + 64 * i] = 0;
        return;
    }
    float v[12];
    float ss = 0.f;
    for (int i = 0; i < 12; ++i) {
        v[i] = protos[(size_t)row * C_ + l + 64 * i];
        ss += v[i] * v[i];
    }
    for (int off = 32; off >= 1; off >>= 1) ss += __shfl_xor(ss, off);
    const float scale = 1.0f / fmaxf(sqrtf(ss), 1e-6f);
    for (int i = 0; i < 12; ++i) {
        __hip_bfloat16 h = __float2bfloat16(v[i] * scale);
        pn[(size_t)row * C_ + l + 64 * i] = *reinterpret_cast<unsigned short*>(&h);
    }
}

// ---------------- main kernel
// Per (b, 64-token chunk): A panel LDS-resident; B triple-buffered via
// global_load_lds + counted vmcnt(2) pipeline; online partial LSE per nt-tile.
__global__ __launch_bounds__(512, 2) void main_kernel(
        const float* __restrict__ feats, const unsigned short* __restrict__ pn,
        const float* __restrict__ log_temp,
        float* __restrict__ wsm, float* __restrict__ wss) {

    __shared__ char  Alds[MT * 1536];       // [t][c] bf16, row 1536B, slot ^= (t&7)^((t>>3)&7)
    __shared__ char  Blds[3 * NT * 128];    // 3 bufs of [n][8 slots*16B]; slot j holds chunk j^(n&7)
    __shared__ float ss_lds[MT];
    __shared__ float scale_lds[MT];
    __shared__ float red[8][2][16][2];
    __shared__ float res[NTILES * NT * 2];  // deferred (M,S) results

    const int tid = threadIdx.x;
    const int l   = tid & 63;
    const int w   = tid >> 6;     // wave 0..7
    const int g   = l >> 4;       // lane group 0..3
    const int lm  = l & 15;
    const int wm  = w >> 2;       // 0..1 (m half)
    const int wn  = w & 3;        // 0..3 (n quarter)

    const int bb = blockIdx.x >> 4;
    const int tc = blockIdx.x & 15;
    const int t0 = tc * MT;

    // ---- B staging: linear LDS dest (gload_lds), pre-swizzled global source.
    // lane l -> row n = base + (l>>3), LDS slot (l&7); loads global chunk (l&7)^(n&7).
    const int sSlot8  = (((l & 7) ^ ((l >> 3) & 7))) * 8;
    const int rowLane = (w * 16 + (l >> 3)) * C_ + sSlot8;
    auto stageB = [&](int rowBase, int colOff, int bufi) {
        const unsigned short* gp = pn + rowBase + rowLane + colOff;
        char* lb = &Blds[bufi * 16384 + w * 2048];
        gload16(gp, lb);                       // rows w*16 + 0..7
        gload16(gp + 8 * C_, lb + 1024);       // rows w*16 + 8..15
    };

    // prologue: stage u=0,1 (overlaps with A-transpose below)
    stageB(0, 0, 0);
    stageB(0, 64, 1);

    if (tid < MT) ss_lds[tid] = 0.f;
    __syncthreads();

    // ---- stage A panel [64 t][768 c] bf16 (transpose from [c][t]); fp32 sum-of-squares
    {
        const int t4 = tid & 15;      // float4 index along t
        const int cq = tid >> 4;      // 0..31
        float ssp[4] = {0.f, 0.f, 0.f, 0.f};
        const float* fb = feats + (size_t)bb * (C_ * T_) + t0 + t4 * 4;
        #pragma unroll
        for (int i = 0; i < 6; ++i) {
            const int c0 = cq * 4 + i * 128;
            unsigned short hb[4][4];  // [q][j]
            #pragma unroll
            for (int j = 0; j < 4; ++j) {
                const float4 v = *reinterpret_cast<const float4*>(fb + (size_t)(c0 + j) * T_);
                const float e[4] = {v.x, v.y, v.z, v.w};
                #pragma unroll
                for (int q = 0; q < 4; ++q) {
                    ssp[q] += e[q] * e[q];
                    __hip_bfloat16 h = __float2bfloat16(e[q]);
                    hb[q][j] = *reinterpret_cast<unsigned short*>(&h);
                }
            }
            #pragma unroll
            for (int q = 0; q < 4; ++q) {
                const int t = t4 * 4 + q;
                unsigned byte = (unsigned)(t * 1536 + c0 * 2);
                byte ^= (unsigned)(((t & 7) ^ ((t >> 3) & 7)) << 4);
                ushort4 pk = {hb[q][0], hb[q][1], hb[q][2], hb[q][3]};
                *reinterpret_cast<ushort4*>(&Alds[byte]) = pk;
            }
        }
        #pragma unroll
        for (int q = 0; q < 4; ++q) {
            ssp[q] += __shfl_xor(ssp[q], 16);
            ssp[q] += __shfl_xor(ssp[q], 32);
        }
        if (l < 16) {
            #pragma unroll
            for (int q = 0; q < 4; ++q) atomicAdd(&ss_lds[l * 4 + q], ssp[q]);
        }
    }
    __syncthreads();
    if (tid < MT) {
        const float temp = fminf(fmaxf(expf(log_temp[0]), 1e-4f), 100.0f);
        scale_lds[tid] = temp / fmaxf(sqrtf(ss_lds[tid]), 1e-6f);
    }
    __syncthreads();

    // ---- pipelined main loop: 1 barrier/step, counted vmcnt, prefetch distance 2
    int bufC = 0;           // compute buffer = u % 3
    int sRB  = 0, sKS = 2;  // next stage coords (u+2): rowBase = nt*NT*C_, ks
    const float tsA0 = 0.f; (void)tsA0;

    for (int nt = 0; nt < NTILES; ++nt) {
        f32x4 acc[2][2] = {};

        for (int ks = 0; ks < KSTEPS; ++ks) {
            const int u = nt * KSTEPS + ks;
            if (u < NSTEPS - 1) {
                asm volatile("s_waitcnt vmcnt(2)" ::: "memory");   // own stage(u) landed
            } else {
                asm volatile("s_waitcnt vmcnt(0)" ::: "memory");
            }
            __builtin_amdgcn_s_barrier();   // everyone's stage(u) landed; prev reads done

            // ds_read fragments of step u
            bf16x8 a[2][2], b[2][2];
            #pragma unroll
            for (int kk = 0; kk < 2; ++kk) {
                #pragma unroll
                for (int mi = 0; mi < 2; ++mi) {
                    const int t = wm * 32 + mi * 16 + lm;
                    unsigned byte = (unsigned)(t * 1536 + (ks * 64 + kk * 32 + g * 8) * 2);
                    byte ^= (unsigned)(((t & 7) ^ ((t >> 3) & 7)) << 4);
                    a[kk][mi] = *reinterpret_cast<const bf16x8*>(&Alds[byte]);
                }
                #pragma unroll
                for (int ni = 0; ni < 2; ++ni) {
                    const int n = wn * 32 + ni * 16 + lm;
                    const int j = (kk * 4 + g) ^ (n & 7);
                    b[kk][ni] = *reinterpret_cast<const bf16x8*>(
                        &Blds[bufC * 16384 + n * 128 + j * 16]);
                }
            }

            // prefetch stage u+2 into buf (u+2)%3  (safe: that buf's readers
            // finished before the barrier above)
            if (u + 2 < NSTEPS) {
                const int bufS = (bufC == 0) ? 2 : bufC - 1;
                stageB(sRB, sKS * 64, bufS);
                if (++sKS == KSTEPS) { sKS = 0; sRB += NT * C_; }
            }

            __builtin_amdgcn_s_setprio(1);
            #pragma unroll
            for (int kk = 0; kk < 2; ++kk)
                #pragma unroll
                for (int mi = 0; mi < 2; ++mi)
                    #pragma unroll
                    for (int ni = 0; ni < 2; ++ni)
                        acc[mi][ni] = __builtin_amdgcn_mfma_f32_16x16x32_bf16(
                            a[kk][mi], b[kk][ni], acc[mi][ni], 0, 0, 0);
            __builtin_amdgcn_s_setprio(0);

            bufC = (bufC == 2) ? 0 : bufC + 1;
        }

        // ---- epilogue: scale by temp/||token||, partial LSE over the 64 t-rows
        float4 sc[2];
        #pragma unroll
        for (int mi = 0; mi < 2; ++mi)
            sc[mi] = *reinterpret_cast<const float4*>(&scale_lds[wm * 32 + mi * 16 + g * 4]);

        #pragma unroll
        for (int ni = 0; ni < 2; ++ni) {
            float vals[8];
            float mloc = -3.0e38f;
            #pragma unroll
            for (int mi = 0; mi < 2; ++mi) {
                const float scv[4] = {sc[mi].x, sc[mi].y, sc[mi].z, sc[mi].w};
                #pragma unroll
                for (int r = 0; r < 4; ++r) {
                    const float v = acc[mi][ni][r] * scv[r];
                    vals[mi * 4 + r] = v;
                    mloc = fmaxf(mloc, v);
                }
            }
            float sloc = 0.f;
            #pragma unroll
            for (int i = 0; i < 8; ++i) sloc += expf(vals[i] - mloc);
            #pragma unroll
            for (int off = 16; off <= 32; off <<= 1) {
                const float mo = __shfl_xor(mloc, off);
                const float so = __shfl_xor(sloc, off);
                const float M = fmaxf(mloc, mo);
                sloc = sloc * expf(mloc - M) + so * expf(mo - M);
                mloc = M;
            }
            if (l < 16) { red[w][ni][lm][0] = mloc; red[w][ni][lm][1] = sloc; }
        }
        asm volatile("s_waitcnt lgkmcnt(0)" ::: "memory");
        __builtin_amdgcn_s_barrier();
        if (wm == 0 && l < 16) {
            #pragma unroll
            for (int ni = 0; ni < 2; ++ni) {
                const float m0 = red[w][ni][lm][0],     s0 = red[w][ni][lm][1];
                const float m1 = red[w + 4][ni][lm][0], s1 = red[w + 4][ni][lm][1];
                const float M = fmaxf(m0, m1);
                const float S = s0 * expf(m0 - M) + s1 * expf(m1 - M);
                const int r = nt * NT + wn * 32 + ni * 16 + lm;
                res[r * 2 + 0] = M;
                res[r * 2 + 1] = S;
            }
        }
        // red reuse protected by the 12 in-loop barriers of the next nt
    }

    asm volatile("s_waitcnt lgkmcnt(0)" ::: "memory");
    __builtin_amdgcn_s_barrier();

    // ---- write deferred results
    const size_t wsbase = ((size_t)bb * TCH + tc) * KPAD;
    for (int e = tid; e < NTILES * NT; e += 512) {
        wsm[wsbase + e] = res[e * 2 + 0];
        wss[wsbase + e] = res[e * 2 + 1];
    }
}

// ---------------- final: joint LSE over 16 chunks x 8 protos per class
__global__ __launch_bounds__(128) void final_kernel(const float* __restrict__ wsm,
                                                    const float* __restrict__ wss,
                                                    float* __restrict__ out) {
    const int b = blockIdx.x;
    const int c = threadIdx.x;
    if (c >= 100) return;
    float M = -3.0e38f, S = 0.f;
    for (int ch = 0; ch < TCH; ++ch) {
        const size_t base = ((size_t)b * TCH + ch) * KPAD + c * 8;
        #pragma unroll
        for (int p = 0; p < 8; ++p) {
            const float m = wsm[base + p], s = wss[base + p];
            const float Mn = fmaxf(M, m);
            S = S * expf(M - Mn) + s * expf(m - Mn);
            M = Mn;
        }
    }
    out[b * 100 + c] = M + logf(S);
}

extern "C" void kernel_launch(void* const* d_in, const int* in_sizes, int n_in,
                              void* d_out, int out_size, void* d_ws, size_t ws_size,
                              hipStream_t stream) {
    (void)in_sizes; (void)n_in; (void)out_size; (void)ws_size;
    const float* feats    = (const float*)d_in[0];
    const float* protos   = (const float*)d_in[1];
    const float* log_temp = (const float*)d_in[2];
    float* out = (float*)d_out;

    unsigned short* pn = (unsigned short*)d_ws;                       // 896*768 bf16
    float* wsm = (float*)((char*)d_ws + (size_t)KPAD * C_ * 2);       // 64*16*896 f32
    float* wss = wsm + (size_t)B_ * TCH * KPAD;

    proto_norm_kernel<<<KPAD, 64, 0, stream>>>(protos, pn);
    main_kernel<<<B_ * TCH, 512, 0, stream>>>(feats, pn, log_temp, wsm, wss);
    final_kernel<<<B_, 128, 0, stream>>>(wsm, wss, out);
}